// Round 6
// baseline (231.649 us; speedup 1.0000x reference)
//
#include <hip/hip_runtime.h>
#include <math.h>

#define N_ENTC 30000
#define ALL_RELC 221
#define NDIM 32
#define EVAL_RELC 86
#define BB 16
#define NE 120000
#define ROW 512            /* BB*NDIM floats per entity row */
#define NSCAN 120          /* scan blocks; NSCAN*EPB == NE */
#define EPB 1000
#define MW 938             /* bitmask words for 30000 entities */
#define CAPM 2048          /* LDS M-list capacity (global fallback beyond) */
#define MAGIC 0x5F3759DFu

// ---------------------------------------------------------------------------
// K1: 120 blocks scan 1000-edge stripes. Qualifying edges are written as
// packed int4 records (plain stores; K2 reads them after the stream-ordered
// dispatch boundary -- no tags, no polls, no fences):
//   list 0 (d=0 L1, eh in H):  {et, rel|(srcmask<<8),  ew_bits, eh}
//   list 1 (d=1 L1, eh in T):  {et, rel|(srcmask<<8),  ew_bits, eh}
//   list 2 (d=0 L2, et in T):  {eh, rel|(canon<<8),    ew_bits, et}
//   list 3 (d=1 L2, et in H):  {eh, rel|(canon<<8),    ew_bits, et}
// srcmask: bit b set iff source-id[b]==eh (handles duplicate batch ids).
// canon: canonical query slot of et (first matching b).
// Block 0 additionally computes relw[2][16][221] -> global; block 1 zeroes qacc.
// ---------------------------------------------------------------------------
__global__ __launch_bounds__(512) void k_scan(
    const int* __restrict__ head, const int* __restrict__ tail,
    const int* __restrict__ eh, const int* __restrict__ et,
    const int* __restrict__ er, const float* __restrict__ ew,
    const float* __restrict__ ent_emb,
    const float* __restrict__ Wrel, const float* __restrict__ brel,
    const float* __restrict__ Watt, const float* __restrict__ batt,
    int4* __restrict__ recs, int* __restrict__ counts,
    float* __restrict__ relwG, float* __restrict__ qaccB)
{
    __shared__ unsigned mH[MW], mT[MW];
    __shared__ int s_src[32];
    __shared__ int s_cnt[4];
    __shared__ float s_ht[BB * 64];
    __shared__ float s_h5[BB * 5];
    const int t = threadIdx.x, bid = blockIdx.x;

    if (t < 32) s_src[t] = (t < BB) ? head[t] : tail[t - BB];
    for (int i = t; i < MW; i += 512) { mH[i] = 0u; mT[i] = 0u; }
    if (t < 4) s_cnt[t] = 0;
    __syncthreads();
    if (t < BB) {
        int h = s_src[t], q = s_src[BB + t];
        atomicOr(&mH[h >> 5], 1u << (h & 31));
        atomicOr(&mT[q >> 5], 1u << (q & 31));
    }
    __syncthreads();

    const int e0 = bid * EPB;
    const int4* eh4 = (const int4*)(eh + e0);
    const int4* et4 = (const int4*)(et + e0);
    for (int p = t; p < EPB / 4; p += 512) {
        int4 h4 = eh4[p], t4 = et4[p];
        int hv[4] = {h4.x, h4.y, h4.z, h4.w};
        int tv[4] = {t4.x, t4.y, t4.z, t4.w};
#pragma unroll
        for (int c = 0; c < 4; c++) {
            int e = e0 + 4 * p + c, h = hv[c], tt = tv[c];
            bool hH = (mH[h >> 5] >> (h & 31)) & 1u;
            bool hT = (mT[h >> 5] >> (h & 31)) & 1u;
            bool tT = (mT[tt >> 5] >> (tt & 31)) & 1u;
            bool tH = (mH[tt >> 5] >> (tt & 31)) & 1u;
            if (!(hH | hT | tT | tH)) continue;
            int r = er[e];
            int wb = __float_as_int(ew[e]);
            if (hH) {
                unsigned m = 0;
#pragma unroll
                for (int b = 0; b < BB; b++) m |= (s_src[b] == h) ? (1u << b) : 0u;
                int pos = atomicAdd(&s_cnt[0], 1);
                recs[(size_t)bid * EPB + pos] = make_int4(tt, r | (int)(m << 8), wb, h);
            }
            if (hT) {
                unsigned m = 0;
#pragma unroll
                for (int b = 0; b < BB; b++) m |= (s_src[BB + b] == h) ? (1u << b) : 0u;
                int pos = atomicAdd(&s_cnt[1], 1);
                recs[(size_t)NE + bid * EPB + pos] = make_int4(tt, r | (int)(m << 8), wb, h);
            }
            if (tT) {
                unsigned m = 0;
#pragma unroll
                for (int b = 0; b < BB; b++) m |= (s_src[BB + b] == tt) ? (1u << b) : 0u;
                int canon = __ffs(m) - 1;
                int pos = atomicAdd(&s_cnt[2], 1);
                recs[(size_t)2 * NE + bid * EPB + pos] = make_int4(h, r | (canon << 8), wb, tt);
            }
            if (tH) {
                unsigned m = 0;
#pragma unroll
                for (int b = 0; b < BB; b++) m |= (s_src[b] == tt) ? (1u << b) : 0u;
                int canon = __ffs(m) - 1;
                int pos = atomicAdd(&s_cnt[3], 1);
                recs[(size_t)3 * NE + bid * EPB + pos] = make_int4(h, r | (canon << 8), wb, tt);
            }
        }
    }
    __syncthreads();
    if (t < 4) counts[bid * 4 + t] = s_cnt[t];

    if (bid == 1) { // zero qacc for both directions
        for (int i = t; i < 2 * BB * ROW; i += 512) qaccB[i] = 0.f;
    }
    if (bid == 0) { // relation-attention weights -> global
        for (int i = t; i < BB * NDIM; i += 512) {
            int b = i >> 5, k = i & 31;
            s_ht[b * 64 + k] = ent_emb[(size_t)s_src[b] * NDIM + k];
            s_ht[b * 64 + 32 + k] = ent_emb[(size_t)s_src[BB + b] * NDIM + k];
        }
        __syncthreads();
        for (int l = 0; l < 2; l++) {
            for (int i = t; i < BB * 5; i += 512) {
                int b = i / 5, j = i % 5;
                float s = brel[l * 5 + j];
                for (int k = 0; k < 64; k++)
                    s += s_ht[b * 64 + k] * Wrel[l * 320 + k * 5 + j];
                s_h5[i] = fmaxf(s, 0.f);
            }
            __syncthreads();
            for (int i = t; i < BB * ALL_RELC; i += 512) {
                int b = i / ALL_RELC, r = i % ALL_RELC;
                float s = batt[l * ALL_RELC + r];
                for (int j = 0; j < 5; j++)
                    s += s_h5[b * 5 + j] * Watt[l * 5 * ALL_RELC + j * ALL_RELC + r];
                relwG[l * BB * ALL_RELC + i] = 1.0f / (1.0f + expf(-s));
            }
            __syncthreads();
        }
    }
}

// ---------------------------------------------------------------------------
// K2: 2 blocks x 1024 threads, one per direction. Pure data-parallel tail over
// the packed record lists; only cross-block sync is the final MAGIC handoff.
// ---------------------------------------------------------------------------
__global__ __launch_bounds__(1024) void k_tail(
    const int* __restrict__ head, const int* __restrict__ tail,
    const float* __restrict__ ent_emb, const float* __restrict__ rel_embs,
    const float* __restrict__ Wlin, const float* __restrict__ blin,
    const float* __restrict__ Wr, const float* __restrict__ br,
    const int4* __restrict__ recs, const int* __restrict__ counts,
    const float* __restrict__ relwG, float* __restrict__ hidB,
    float* __restrict__ qaccB, int* __restrict__ gMl,
    float* __restrict__ staging, unsigned* __restrict__ hflag,
    float* __restrict__ out)
{
    __shared__ float s_relw[7072];  // layer0 @0, layer1 @3536; reused in final
    __shared__ float s_W[2048];
    __shared__ float s_b[64];
    __shared__ float s_ht[1024];    // [b][head 32 | tail 32]
    __shared__ int s_src[32];
    __shared__ int s_cnts[2 * NSCAN]; // [2i]=L1 cnt of stripe i, [2i+1]=L2 cnt
    __shared__ unsigned mM[MW];
    __shared__ int s_Ml[CAPM];
    __shared__ int s_cm;
    __shared__ int s_canon[BB];

    const int t = threadIdx.x, d = blockIdx.x;
    const int wid = t >> 6, lane = t & 63;
    const int nw = 1024 / 64;
    float* hB = hidB + (size_t)d * N_ENTC * ROW;
    float* qacc = qaccB + (size_t)d * BB * ROW;
    int* gml = gMl + (size_t)d * N_ENTC;

    if (t < 32) s_src[t] = (t < BB) ? head[t] : tail[t - BB];
    for (int i = t; i < 7072; i += 1024) s_relw[i] = relwG[i];
    for (int i = t; i < 2048; i += 1024) s_W[i] = Wlin[i];
    if (t < 64) s_b[t] = blin[t];
    for (int i = t; i < MW; i += 1024) mM[i] = 0u;
    if (t == 0) s_cm = 0;
    for (int i = t; i < NSCAN; i += 1024) {
        s_cnts[2 * i] = counts[4 * i + d];
        s_cnts[2 * i + 1] = counts[4 * i + 2 + d];
    }
    __syncthreads();
    if (t < BB * NDIM) {
        int b = t >> 5, k = t & 31;
        s_ht[b * 64 + k] = ent_emb[(size_t)s_src[b] * NDIM + k];
        s_ht[b * 64 + 32 + k] = ent_emb[(size_t)s_src[BB + b] * NDIM + k];
    }
    if (t < BB) {
        int q = s_src[(1 - d) * BB + t];
        int c = 0;
        for (int bb = 0; bb < BB; bb++)
            if (s_src[(1 - d) * BB + bb] == q) { c = bb; break; }
        s_canon[t] = c;
    }
    __syncthreads();

    // Phase A: M = distinct heads of L2 records
    const int4* R2 = recs + (size_t)(2 + d) * NE;
    for (int i = wid; i < NSCAN; i += nw) {
        int c = s_cnts[2 * i + 1];
        for (int k = lane; k < c; k += 64) {
            int h = R2[(size_t)i * EPB + k].x;
            unsigned bit = 1u << (h & 31);
            unsigned old = atomicOr(&mM[h >> 5], bit);
            if (!(old & bit)) {
                int pos = atomicAdd(&s_cm, 1);
                if (pos < CAPM) s_Ml[pos] = h; else gml[pos - CAPM] = h;
            }
        }
    }
    __syncthreads();
    const int cm = s_cm;

    // Phase B: zero hidB rows of M
    {
        float4 z = make_float4(0.f, 0.f, 0.f, 0.f);
        for (int j = wid; j < cm; j += nw) {
            int row = (j < CAPM) ? s_Ml[j] : gml[j - CAPM];
            float4* p = (float4*)(hB + (size_t)row * ROW);
            p[lane] = z;
            p[lane + 64] = z;
        }
    }
    __syncthreads();

    // Phase C: layer-1 messages (sources from LDS s_ht, targets filtered by M)
    const int4* R1 = recs + (size_t)d * NE;
    const float4* rv0 = (const float4*)rel_embs;
    for (int i = wid; i < NSCAN; i += nw) {
        int c = s_cnts[2 * i];
        for (int k = 0; k < c; k++) {
            int4 rec = R1[(size_t)i * EPB + k];
            int tt = rec.x;
            if (!((mM[tt >> 5] >> (tt & 31)) & 1u)) continue;
            int r = rec.y & 255;
            unsigned msk = ((unsigned)rec.y) >> 8;
            float w = __int_as_float(rec.z);
            float* drow = hB + (size_t)tt * ROW;
#pragma unroll
            for (int ii = 0; ii < 2; ii++) {
                int i4 = lane + 64 * ii, b = i4 >> 3, kq = i4 & 7;
                if (!((msk >> b) & 1u)) continue;
                float c1 = s_relw[b * ALL_RELC + r] * w;
                float4 sv4 = *(const float4*)&s_ht[b * 64 + d * 32 + kq * 4];
                float4 rr = rv0[r * 8 + kq];
                atomicAdd(drow + i4 * 4 + 0, sv4.x * c1 * rr.x);
                atomicAdd(drow + i4 * 4 + 1, sv4.y * c1 * rr.y);
                atomicAdd(drow + i4 * 4 + 2, sv4.z * c1 * rr.z);
                atomicAdd(drow + i4 * 4 + 3, sv4.w * c1 * rr.w);
            }
        }
    }
    __syncthreads();

    // Phase D: layer-1 linear in-place on M rows
    {
        int b = lane >> 2, j0 = (lane & 3) * 8;
        for (int j = wid; j < cm; j += nw) {
            int row = (j < CAPM) ? s_Ml[j] : gml[j - CAPM];
            float* rowp = hB + (size_t)row * ROW + b * NDIM;
            const float4* src = (const float4*)rowp;
            float h[NDIM];
#pragma unroll
            for (int q = 0; q < 8; q++) {
                float4 v = src[q];
                h[q * 4 + 0] = v.x; h[q * 4 + 1] = v.y;
                h[q * 4 + 2] = v.z; h[q * 4 + 3] = v.w;
            }
            float acc[8];
#pragma unroll
            for (int jj = 0; jj < 8; jj++) acc[jj] = s_b[j0 + jj];
#pragma unroll
            for (int k = 0; k < NDIM; k++) {
                float4 w0 = *(const float4*)&s_W[k * NDIM + j0];
                float4 w1 = *(const float4*)&s_W[k * NDIM + j0 + 4];
                float hk = h[k];
                acc[0] += hk * w0.x; acc[1] += hk * w0.y;
                acc[2] += hk * w0.z; acc[3] += hk * w0.w;
                acc[4] += hk * w1.x; acc[5] += hk * w1.y;
                acc[6] += hk * w1.z; acc[7] += hk * w1.w;
            }
            float4 o0, o1;
            o0.x = fmaxf(acc[0], 0.f); o0.y = fmaxf(acc[1], 0.f);
            o0.z = fmaxf(acc[2], 0.f); o0.w = fmaxf(acc[3], 0.f);
            o1.x = fmaxf(acc[4], 0.f); o1.y = fmaxf(acc[5], 0.f);
            o1.z = fmaxf(acc[6], 0.f); o1.w = fmaxf(acc[7], 0.f);
            *(float4*)(rowp + j0) = o0;
            *(float4*)(rowp + j0 + 4) = o1;
        }
    }
    __syncthreads();

    // Phase E: layer-2 messages hidB[M] -> qacc (canonical query rows)
    const float4* rv1 = (const float4*)(rel_embs + (size_t)ALL_RELC * NDIM);
    for (int i = wid; i < NSCAN; i += nw) {
        int c = s_cnts[2 * i + 1];
        for (int k = 0; k < c; k++) {
            int4 rec = R2[(size_t)i * EPB + k];
            int h = rec.x, r = rec.y & 255, canon = (rec.y >> 8) & 15;
            float w = __int_as_float(rec.z);
            const float4* srow = (const float4*)(hB + (size_t)h * ROW);
            float* drow = qacc + canon * ROW;
#pragma unroll
            for (int ii = 0; ii < 2; ii++) {
                int i4 = lane + 64 * ii, b = i4 >> 3, kq = i4 & 7;
                float c1 = s_relw[3536 + b * ALL_RELC + r] * w;
                float4 s = srow[i4];
                float4 rr = rv1[r * 8 + kq];
                atomicAdd(drow + i4 * 4 + 0, s.x * c1 * rr.x);
                atomicAdd(drow + i4 * 4 + 1, s.y * c1 * rr.y);
                atomicAdd(drow + i4 * 4 + 2, s.z * c1 * rr.z);
                atomicAdd(drow + i4 * 4 + 3, s.w * c1 * rr.w);
            }
        }
    }
    __syncthreads();

    // Phase F: layer-2 linear, only (canon(q_b), sample b) segments
    if (t < 512) {
        int b = t >> 5, j = t & 31;
        const float* hrow = qacc + s_canon[b] * ROW + b * NDIM;
        float s = s_b[NDIM + j];
        for (int k = 0; k < NDIM; k++)
            s += hrow[k] * s_W[NDIM * NDIM + k * NDIM + j];
        float val = fmaxf(s, 0.f);
        if (d == 1) staging[512 + t] = val;
        else s_relw[t] = val; // block 0 stashes tail_hid in LDS (relw dead)
    }
    __syncthreads();

    // cross-block handoff (proven pattern) + final GEMM on block 0
    if (d == 1) {
        if (t == 0) {
            __builtin_amdgcn_fence(__ATOMIC_RELEASE, "agent");
            __hip_atomic_store(hflag, MAGIC, __ATOMIC_RELAXED,
                               __HIP_MEMORY_SCOPE_AGENT);
        }
        return;
    }
    if (t == 0) {
        while (__hip_atomic_load(hflag, __ATOMIC_RELAXED,
                                 __HIP_MEMORY_SCOPE_AGENT) != MAGIC)
            __builtin_amdgcn_s_sleep(8);
        __builtin_amdgcn_fence(__ATOMIC_ACQUIRE, "agent");
    }
    __syncthreads();

    float* sx = s_relw + 1024; // [16][128] = hemb|temb|head_hid|tail_hid
    if (t < 512) {
        int b = t >> 5, k = t & 31;
        sx[b * 128 + k] = s_ht[b * 64 + k];
        sx[b * 128 + 32 + k] = s_ht[b * 64 + 32 + k];
        sx[b * 128 + 64 + k] = staging[512 + b * 32 + k]; // head_hid (dir 1)
        sx[b * 128 + 96 + k] = s_relw[b * 32 + k];        // tail_hid (dir 0)
    }
    __syncthreads();
    for (int o = t; o < BB * EVAL_RELC; o += 1024) {
        int b = o / EVAL_RELC, r = o % EVAL_RELC;
        float s = br[r];
        for (int k = 0; k < 128; k++)
            s += sx[b * 128 + k] * Wr[k * EVAL_RELC + r];
        out[o] = s;
    }
}

extern "C" void kernel_launch(void* const* d_in, const int* in_sizes, int n_in,
                              void* d_out, int out_size, void* d_ws,
                              size_t ws_size, hipStream_t stream)
{
    const int* head = (const int*)d_in[0];
    const int* tail = (const int*)d_in[1];
    const int* eh = (const int*)d_in[2];
    const int* et = (const int*)d_in[3];
    const int* er = (const int*)d_in[4];
    const float* ew = (const float*)d_in[5];
    const float* ent_emb = (const float*)d_in[6];
    const float* rel_embs = (const float*)d_in[7];
    const float* Wlin = (const float*)d_in[8];
    const float* blin = (const float*)d_in[9];
    const float* Wrel = (const float*)d_in[10];
    const float* brel = (const float*)d_in[11];
    const float* Watt = (const float*)d_in[12];
    const float* batt = (const float*)d_in[13];
    const float* Wr = (const float*)d_in[14];
    const float* br = (const float*)d_in[15];
    float* out = (float*)d_out;
    float* ws = (float*)d_ws;

    // ---- workspace carve (~131 MB) ----
    float* hidB = ws;                                        // [2][N][ROW]
    int4* recs = (int4*)(hidB + (size_t)2 * N_ENTC * ROW);   // [4][NE] int4
    int* counts = (int*)(recs + (size_t)4 * NE);             // [NSCAN][4]
    float* relwG = (float*)(counts + 4 * NSCAN);             // 7072
    float* qaccB = relwG + 7072;                             // [2][16][512]
    int* gMl = (int*)(qaccB + 2 * BB * ROW);                 // [2][N]
    float* staging = (float*)(gMl + (size_t)2 * N_ENTC);     // [2][512]
    unsigned* hflag = (unsigned*)(staging + 1024);

    k_scan<<<NSCAN, 512, 0, stream>>>(head, tail, eh, et, er, ew, ent_emb,
                                      Wrel, brel, Watt, batt,
                                      recs, counts, relwG, qaccB);
    k_tail<<<2, 1024, 0, stream>>>(head, tail, ent_emb, rel_embs, Wlin, blin,
                                   Wr, br, recs, counts, relwG, hidB, qaccB,
                                   gMl, staging, hflag, out);
}

// Round 7
// 119.916 us; speedup vs baseline: 1.9318x; 1.9318x over previous
//
#include <hip/hip_runtime.h>
#include <math.h>

#define N_ENTC 30000
#define ALL_RELC 221
#define NDIM 32
#define EVAL_RELC 86
#define BB 16
#define NE 120000
#define ROW 512            /* BB*NDIM floats per entity row */
#define NSCAN 120          /* scan blocks; NSCAN*EPB == NE */
#define EPB 1000
#define MW 938             /* bitmask words for 30000 entities */

// Pipeline (stream order = all sync; every kernel wide-parallel, no polls):
//  K1 k_scan : 120 blocks. Records per stripe (R6-proven packed int4 format),
//              counts, idempotent zero of hidB rows for L2-record heads,
//              block0: relw -> global, block1: zero qacc.
//  K2 k_msg1 : 120 blocks. Layer-1 messages (sources = ent_emb via srcmask)
//              atomically accumulated into hidB (rows for L2-heads are zeroed;
//              messages into other rows are never read -- harmless).
//  K3 k_lin1 : 120 blocks. Per L2 record: hidC[h] = relu(hidB[h]@W0 + b0).
//              Duplicate heads write identical bytes (pure function).
//  K4 k_msg2 : 120 blocks. Layer-2 messages hidC[h] -> qacc[canon slot].
//  K5 k_fin  : 1 block. Layer-2 linear on (canon,b) segments + gather + GEMM.

__global__ __launch_bounds__(512) void k_scan(
    const int* __restrict__ head, const int* __restrict__ tail,
    const int* __restrict__ eh, const int* __restrict__ et,
    const int* __restrict__ er, const float* __restrict__ ew,
    const float* __restrict__ ent_emb,
    const float* __restrict__ Wrel, const float* __restrict__ brel,
    const float* __restrict__ Watt, const float* __restrict__ batt,
    int4* __restrict__ recs, int* __restrict__ counts,
    float* __restrict__ relwG, float* __restrict__ hidB,
    float* __restrict__ qaccB)
{
    __shared__ unsigned mH[MW], mT[MW];
    __shared__ int s_src[32];
    __shared__ int s_cnt[4];
    __shared__ float s_ht[BB * 64];
    __shared__ float s_h5[BB * 5];
    const int t = threadIdx.x, bid = blockIdx.x;

    if (t < 32) s_src[t] = (t < BB) ? head[t] : tail[t - BB];
    for (int i = t; i < MW; i += 512) { mH[i] = 0u; mT[i] = 0u; }
    if (t < 4) s_cnt[t] = 0;
    __syncthreads();
    if (t < BB) {
        int h = s_src[t], q = s_src[BB + t];
        atomicOr(&mH[h >> 5], 1u << (h & 31));
        atomicOr(&mT[q >> 5], 1u << (q & 31));
    }
    __syncthreads();

    const int e0 = bid * EPB;
    const int4* eh4 = (const int4*)(eh + e0);
    const int4* et4 = (const int4*)(et + e0);
    for (int p = t; p < EPB / 4; p += 512) {
        int4 h4 = eh4[p], t4 = et4[p];
        int hv[4] = {h4.x, h4.y, h4.z, h4.w};
        int tv[4] = {t4.x, t4.y, t4.z, t4.w};
#pragma unroll
        for (int c = 0; c < 4; c++) {
            int e = e0 + 4 * p + c, h = hv[c], tt = tv[c];
            bool hH = (mH[h >> 5] >> (h & 31)) & 1u;
            bool hT = (mT[h >> 5] >> (h & 31)) & 1u;
            bool tT = (mT[tt >> 5] >> (tt & 31)) & 1u;
            bool tH = (mH[tt >> 5] >> (tt & 31)) & 1u;
            if (!(hH | hT | tT | tH)) continue;
            int r = er[e];
            int wb = __float_as_int(ew[e]);
            if (hH) { // d=0 layer-1: srcmask over head ids
                unsigned m = 0;
#pragma unroll
                for (int b = 0; b < BB; b++) m |= (s_src[b] == h) ? (1u << b) : 0u;
                int pos = atomicAdd(&s_cnt[0], 1);
                recs[(size_t)bid * EPB + pos] = make_int4(tt, r | (int)(m << 8), wb, h);
            }
            if (hT) { // d=1 layer-1: srcmask over tail ids
                unsigned m = 0;
#pragma unroll
                for (int b = 0; b < BB; b++) m |= (s_src[BB + b] == h) ? (1u << b) : 0u;
                int pos = atomicAdd(&s_cnt[1], 1);
                recs[(size_t)NE + bid * EPB + pos] = make_int4(tt, r | (int)(m << 8), wb, h);
            }
            if (tT) { // d=0 layer-2: canon = first matching tail slot
                unsigned m = 0;
#pragma unroll
                for (int b = 0; b < BB; b++) m |= (s_src[BB + b] == tt) ? (1u << b) : 0u;
                int canon = __ffs(m) - 1;
                int pos = atomicAdd(&s_cnt[2], 1);
                recs[(size_t)2 * NE + bid * EPB + pos] = make_int4(h, r | (canon << 8), wb, tt);
            }
            if (tH) { // d=1 layer-2: canon = first matching head slot
                unsigned m = 0;
#pragma unroll
                for (int b = 0; b < BB; b++) m |= (s_src[b] == tt) ? (1u << b) : 0u;
                int canon = __ffs(m) - 1;
                int pos = atomicAdd(&s_cnt[3], 1);
                recs[(size_t)3 * NE + bid * EPB + pos] = make_int4(h, r | (canon << 8), wb, tt);
            }
        }
    }
    __syncthreads();
    if (t < 4) counts[bid * 4 + t] = s_cnt[t];

    // Idempotent zero of hidB rows for this stripe's L2-record heads.
    {
        const int wid8 = t >> 6, lane = t & 63;
        float4 z = make_float4(0.f, 0.f, 0.f, 0.f);
        for (int li = 2; li < 4; li++) {
            int c = s_cnt[li];
            float* hb = hidB + (size_t)(li - 2) * N_ENTC * ROW;
            for (int j = wid8; j < c; j += 8) {
                int row = recs[(size_t)li * NE + bid * EPB + j].x;
                float4* p = (float4*)(hb + (size_t)row * ROW);
                p[lane] = z;
                p[lane + 64] = z;
            }
        }
    }

    if (bid == 1) { // zero qacc (both directions)
        for (int i = t; i < 2 * BB * ROW; i += 512) qaccB[i] = 0.f;
    }
    if (bid == 0) { // relation-attention weights -> global (R6-proven math)
        for (int i = t; i < BB * NDIM; i += 512) {
            int b = i >> 5, k = i & 31;
            s_ht[b * 64 + k] = ent_emb[(size_t)s_src[b] * NDIM + k];
            s_ht[b * 64 + 32 + k] = ent_emb[(size_t)s_src[BB + b] * NDIM + k];
        }
        __syncthreads();
        for (int l = 0; l < 2; l++) {
            for (int i = t; i < BB * 5; i += 512) {
                int b = i / 5, j = i % 5;
                float s = brel[l * 5 + j];
                for (int k = 0; k < 64; k++)
                    s += s_ht[b * 64 + k] * Wrel[l * 320 + k * 5 + j];
                s_h5[i] = fmaxf(s, 0.f);
            }
            __syncthreads();
            for (int i = t; i < BB * ALL_RELC; i += 512) {
                int b = i / ALL_RELC, r = i % ALL_RELC;
                float s = batt[l * ALL_RELC + r];
                for (int j = 0; j < 5; j++)
                    s += s_h5[b * 5 + j] * Watt[l * 5 * ALL_RELC + j * ALL_RELC + r];
                relwG[l * BB * ALL_RELC + i] = 1.0f / (1.0f + expf(-s));
            }
            __syncthreads();
        }
    }
}

__global__ __launch_bounds__(256) void k_msg1(
    const int* __restrict__ head, const int* __restrict__ tail,
    const float* __restrict__ ent_emb, const float* __restrict__ rel_embs,
    const int4* __restrict__ recs, const int* __restrict__ counts,
    const float* __restrict__ relwG, float* __restrict__ hidB)
{
    __shared__ int s_src[32];
    const int t = threadIdx.x, bid = blockIdx.x;
    int4 c4 = ((const int4*)counts)[bid];
    if ((c4.x | c4.y) == 0) return;
    if (t < 32) s_src[t] = (t < BB) ? head[t] : tail[t - BB];
    __syncthreads();
    const int wid = t >> 6, lane = t & 63;
    const float4* rv0 = (const float4*)rel_embs;
    for (int d = 0; d < 2; d++) {
        int c = d ? c4.y : c4.x;
        const int4* R = recs + (size_t)d * NE + (size_t)bid * EPB;
        float* hb = hidB + (size_t)d * N_ENTC * ROW;
        for (int j = wid; j < c; j += 4) {
            int4 rec = R[j];
            int tt = rec.x, r = rec.y & 255;
            unsigned msk = ((unsigned)rec.y) >> 8;
            float w = __int_as_float(rec.z);
            float* drow = hb + (size_t)tt * ROW;
#pragma unroll
            for (int ii = 0; ii < 2; ii++) {
                int i4 = lane + 64 * ii, b = i4 >> 3, kq = i4 & 7;
                if (!((msk >> b) & 1u)) continue;
                float cf = relwG[b * ALL_RELC + r] * w;
                float4 sv = ((const float4*)(ent_emb + (size_t)s_src[d * BB + b] * NDIM))[kq];
                float4 rr = rv0[r * 8 + kq];
                atomicAdd(drow + i4 * 4 + 0, sv.x * cf * rr.x);
                atomicAdd(drow + i4 * 4 + 1, sv.y * cf * rr.y);
                atomicAdd(drow + i4 * 4 + 2, sv.z * cf * rr.z);
                atomicAdd(drow + i4 * 4 + 3, sv.w * cf * rr.w);
            }
        }
    }
}

__global__ __launch_bounds__(256) void k_lin1(
    const int4* __restrict__ recs, const int* __restrict__ counts,
    const float* __restrict__ Wlin, const float* __restrict__ blin,
    const float* __restrict__ hidB, float* __restrict__ hidC)
{
    __shared__ float sW[NDIM * NDIM];
    __shared__ float sb[NDIM];
    const int t = threadIdx.x, bid = blockIdx.x;
    int4 c4 = ((const int4*)counts)[bid];
    if ((c4.z | c4.w) == 0) return;
    for (int i = t; i < NDIM * NDIM; i += 256) sW[i] = Wlin[i]; // layer 0
    if (t < NDIM) sb[t] = blin[t];
    __syncthreads();
    const int wid = t >> 6, lane = t & 63;
    int b = lane >> 2, j0 = (lane & 3) * 8;
    for (int d = 0; d < 2; d++) {
        int c = d ? c4.w : c4.z;
        const int4* R = recs + (size_t)(2 + d) * NE + (size_t)bid * EPB;
        const float* hb = hidB + (size_t)d * N_ENTC * ROW;
        float* hc = hidC + (size_t)d * N_ENTC * ROW;
        for (int j = wid; j < c; j += 4) {
            int row = R[j].x;
            const float4* src = (const float4*)(hb + (size_t)row * ROW + b * NDIM);
            float h[NDIM];
#pragma unroll
            for (int q = 0; q < 8; q++) {
                float4 v = src[q];
                h[q * 4 + 0] = v.x; h[q * 4 + 1] = v.y;
                h[q * 4 + 2] = v.z; h[q * 4 + 3] = v.w;
            }
            float acc[8];
#pragma unroll
            for (int jj = 0; jj < 8; jj++) acc[jj] = sb[j0 + jj];
#pragma unroll
            for (int k = 0; k < NDIM; k++) {
                float4 w0 = *(const float4*)&sW[k * NDIM + j0];
                float4 w1 = *(const float4*)&sW[k * NDIM + j0 + 4];
                float hk = h[k];
                acc[0] += hk * w0.x; acc[1] += hk * w0.y;
                acc[2] += hk * w0.z; acc[3] += hk * w0.w;
                acc[4] += hk * w1.x; acc[5] += hk * w1.y;
                acc[6] += hk * w1.z; acc[7] += hk * w1.w;
            }
            float* dst = hc + (size_t)row * ROW + b * NDIM;
            float4 o0, o1;
            o0.x = fmaxf(acc[0], 0.f); o0.y = fmaxf(acc[1], 0.f);
            o0.z = fmaxf(acc[2], 0.f); o0.w = fmaxf(acc[3], 0.f);
            o1.x = fmaxf(acc[4], 0.f); o1.y = fmaxf(acc[5], 0.f);
            o1.z = fmaxf(acc[6], 0.f); o1.w = fmaxf(acc[7], 0.f);
            *(float4*)(dst + j0) = o0;
            *(float4*)(dst + j0 + 4) = o1;
        }
    }
}

__global__ __launch_bounds__(256) void k_msg2(
    const int4* __restrict__ recs, const int* __restrict__ counts,
    const float* __restrict__ rel_embs, const float* __restrict__ relwG,
    const float* __restrict__ hidC, float* __restrict__ qaccB)
{
    const int t = threadIdx.x, bid = blockIdx.x;
    int4 c4 = ((const int4*)counts)[bid];
    if ((c4.z | c4.w) == 0) return;
    const int wid = t >> 6, lane = t & 63;
    const float4* rv1 = (const float4*)(rel_embs + (size_t)ALL_RELC * NDIM);
    for (int d = 0; d < 2; d++) {
        int c = d ? c4.w : c4.z;
        const int4* R = recs + (size_t)(2 + d) * NE + (size_t)bid * EPB;
        const float* hc = hidC + (size_t)d * N_ENTC * ROW;
        float* qa = qaccB + (size_t)d * BB * ROW;
        for (int j = wid; j < c; j += 4) {
            int4 rec = R[j];
            int h = rec.x, r = rec.y & 255, canon = (rec.y >> 8) & 15;
            float w = __int_as_float(rec.z);
            const float4* srow = (const float4*)(hc + (size_t)h * ROW);
            float* drow = qa + canon * ROW;
#pragma unroll
            for (int ii = 0; ii < 2; ii++) {
                int i4 = lane + 64 * ii, b = i4 >> 3, kq = i4 & 7;
                float cf = relwG[BB * ALL_RELC + b * ALL_RELC + r] * w;
                float4 s = srow[i4];
                float4 rr = rv1[r * 8 + kq];
                atomicAdd(drow + i4 * 4 + 0, s.x * cf * rr.x);
                atomicAdd(drow + i4 * 4 + 1, s.y * cf * rr.y);
                atomicAdd(drow + i4 * 4 + 2, s.z * cf * rr.z);
                atomicAdd(drow + i4 * 4 + 3, s.w * cf * rr.w);
            }
        }
    }
}

__global__ __launch_bounds__(512) void k_fin(
    const int* __restrict__ head, const int* __restrict__ tail,
    const float* __restrict__ ent_emb, const float* __restrict__ Wlin,
    const float* __restrict__ blin, const float* __restrict__ Wr,
    const float* __restrict__ br, const float* __restrict__ qaccB,
    float* __restrict__ out)
{
    __shared__ float sx[BB * 128]; // hemb|temb|head_hid|tail_hid
    __shared__ float sW[NDIM * NDIM];
    __shared__ float sb[NDIM];
    __shared__ int s_src[32];
    __shared__ int s_canon[2][BB];
    const int t = threadIdx.x;

    if (t < 32) s_src[t] = (t < BB) ? head[t] : tail[t - BB];
    for (int i = t; i < NDIM * NDIM; i += 512) sW[i] = Wlin[NDIM * NDIM + i]; // layer 1
    if (t < NDIM) sb[t] = blin[NDIM + t];
    __syncthreads();
    if (t < 2 * BB) {
        int d = t >> 4, b = t & 15;
        int q = s_src[(1 - d) * BB + b];
        int c = 0;
        for (int bb = 0; bb < BB; bb++)
            if (s_src[(1 - d) * BB + bb] == q) { c = bb; break; }
        s_canon[d][b] = c;
    }
    {
        int b = t >> 5, k = t & 31;
        sx[b * 128 + k] = ent_emb[(size_t)s_src[b] * NDIM + k];           // hemb
        sx[b * 128 + 32 + k] = ent_emb[(size_t)s_src[BB + b] * NDIM + k]; // temb
    }
    __syncthreads();
    for (int d = 0; d < 2; d++) { // layer-2 linear on (canon,b) segments
        int b = t >> 5, j = t & 31;
        const float* hrow = qaccB + (size_t)d * BB * ROW + s_canon[d][b] * ROW + b * NDIM;
        float s = sb[j];
        for (int k = 0; k < NDIM; k++)
            s += hrow[k] * sW[k * NDIM + j];
        // d=0 (init=head, query=tail) -> tail_hid (col 96); d=1 -> head_hid (col 64)
        sx[b * 128 + (d == 0 ? 96 : 64) + j] = fmaxf(s, 0.f);
    }
    __syncthreads();
    for (int o = t; o < BB * EVAL_RELC; o += 512) {
        int b = o / EVAL_RELC, r = o % EVAL_RELC;
        float s = br[r];
        for (int k = 0; k < 128; k++)
            s += sx[b * 128 + k] * Wr[k * EVAL_RELC + r];
        out[o] = s;
    }
}

extern "C" void kernel_launch(void* const* d_in, const int* in_sizes, int n_in,
                              void* d_out, int out_size, void* d_ws,
                              size_t ws_size, hipStream_t stream)
{
    const int* head = (const int*)d_in[0];
    const int* tail = (const int*)d_in[1];
    const int* eh = (const int*)d_in[2];
    const int* et = (const int*)d_in[3];
    const int* er = (const int*)d_in[4];
    const float* ew = (const float*)d_in[5];
    const float* ent_emb = (const float*)d_in[6];
    const float* rel_embs = (const float*)d_in[7];
    const float* Wlin = (const float*)d_in[8];
    const float* blin = (const float*)d_in[9];
    const float* Wrel = (const float*)d_in[10];
    const float* brel = (const float*)d_in[11];
    const float* Watt = (const float*)d_in[12];
    const float* batt = (const float*)d_in[13];
    const float* Wr = (const float*)d_in[14];
    const float* br = (const float*)d_in[15];
    float* out = (float*)d_out;
    float* ws = (float*)d_ws;

    // ---- workspace carve (~253.5 MB of 256 MiB) ----
    float* hidB = ws;                                        // [2][N][ROW]
    float* hidC = hidB + (size_t)2 * N_ENTC * ROW;           // [2][N][ROW]
    int4* recs = (int4*)(hidC + (size_t)2 * N_ENTC * ROW);   // [4][NE] int4
    int* counts = (int*)(recs + (size_t)4 * NE);             // [NSCAN][4]
    float* relwG = (float*)(counts + 4 * NSCAN);             // 7072
    float* qaccB = relwG + 7072;                             // [2][16][512]

    k_scan<<<NSCAN, 512, 0, stream>>>(head, tail, eh, et, er, ew, ent_emb,
                                      Wrel, brel, Watt, batt,
                                      recs, counts, relwG, hidB, qaccB);
    k_msg1<<<NSCAN, 256, 0, stream>>>(head, tail, ent_emb, rel_embs,
                                      recs, counts, relwG, hidB);
    k_lin1<<<NSCAN, 256, 0, stream>>>(recs, counts, Wlin, blin, hidB, hidC);
    k_msg2<<<NSCAN, 256, 0, stream>>>(recs, counts, rel_embs, relwG,
                                      hidC, qaccB);
    k_fin<<<1, 512, 0, stream>>>(head, tail, ent_emb, Wlin, blin, Wr, br,
                                 qaccB, out);
}